// Round 2
// baseline (199.698 us; speedup 1.0000x reference)
//
#include <hip/hip_runtime.h>
#include <stdint.h>

// Simple exponential smoothing: level_t = (1-a)*level_{t-1} + a*y_t,
// level_0 = y_0 pinned via global initial carry s_{-1} = y_0.
// out[t] = level_t for t in [0, n-2].
//
// R10: windowed-carry (R9) rebuilt as a LEAN STREAMING kernel.
//   R9 post-mortem: emit was latency-bound (occ 24%, VALUBusy 6%, HBM 36%)
//   from (a) register spill of the 64-float tile cache (VGPR=64 reported,
//   WRITE_SIZE 105MB = 64 out + ~41 scratch) and (b) grid cap G=1024 ->
//   max 4 blocks/CU by grid size alone.
//   Fixes: no register tile cache (phase C RE-READS input; L2/L3-hot from
//   phase A), no 33KB LDS stage (direct float4 stores; same-thread
//   consecutive stores share a 64B line -> L2 write-combines; must be
//   non-NT), shuffle-based affine scans (16 barriers -> ~4), SEG 64->32 so
//   G=2048 -> 8 blocks/CU (32 waves/CU = occupancy max for 256-thr blocks).
//   Fast path iff (1-a)^4096 < 1e-8 (alpha > ~4.5e-3): per-block carry from
//   a 4096-elem halo; truncation <= 1e-8*|level|, ~3 orders under absmax
//   margin. Exact 2-pass aggregate path kept for tiny alpha (k_block_agg
//   early-exits on the fast path, so no aggregate traffic when fast).
//   XCD swizzle (bijective, G%8==0): consecutive tiles on one XCD so the
//   halo (= tail of tile i-1) hits local L2.
// Bans (measured): in-kernel grid sync (R2 ~80us, R7 ~125us — cross-XCD
// coherence), coop launch (R4: graph-capture reject).
//
// Affine pairs (a,b): s_out = a*s_in + b.
// combine(earlier=(a1,b1), later=(a2,b2)) = (a1*a2, a2*b1 + b2).

#define BLOCK 256
#define SEG   32                  // elements per thread
#define VPT   (SEG / 4)           // 8 float4 per thread
#define CHUNK (BLOCK * SEG)       // 8192 elements per block
#define HALO  4096                // windowed-carry history length
#define HSEG  (HALO / BLOCK)      // 16 halo elements per thread
#define HVPT  (HSEG / 4)          // 4 float4 per thread for halo
#define DECAY_THR 1e-8f           // fast path iff (1-a)^HALO < this

// x^(2^k) via repeated squaring
__device__ __forceinline__ float pow2k(float x, int k) {
    float p = x;
#pragma unroll
    for (int i = 0; i < k; ++i) p *= p;
    return p;
}

// Inclusive affine scan across the 64 lanes of a wave (shuffle-based, no LDS).
// Affine order = ascending lane. combine(earlier, later) as above.
__device__ __forceinline__ void wave_scan_affine(float& a, float& b) {
    const int lane = threadIdx.x & 63;
#pragma unroll
    for (int off = 1; off < 64; off <<= 1) {
        float pa = __shfl_up(a, off);
        float pb = __shfl_up(b, off);
        if (lane >= off) {
            b = fmaf(a, pb, b);   // later.a * earlier.b + later.b
            a = pa * a;
        }
    }
}

// Block-wide EXCLUSIVE affine scan (identity for t=0).
// wa/wb: 4-element LDS scratch for wave totals. Caller must ensure wa/wb are
// not being read by a prior phase (barrier before call if reused).
// After return, wa/wb hold the 4 wave totals (valid until next reuse).
__device__ __forceinline__ void block_exscan_affine(
    float a, float b, float* wa, float* wb, int t, float& ea, float& eb)
{
    float ia = a, ib = b;
    wave_scan_affine(ia, ib);                 // inclusive within wave
    const int w = t >> 6, lane = t & 63;
    if (lane == 63) { wa[w] = ia; wb[w] = ib; }
    // exclusive within wave
    float xa = __shfl_up(ia, 1);
    float xb = __shfl_up(ib, 1);
    if (lane == 0) { xa = 1.0f; xb = 0.0f; }
    __syncthreads();
    float pa = 1.0f, pb = 0.0f;               // compose waves 0..w-1 in order
#pragma unroll
    for (int i = 0; i < 3; ++i) {
        if (i < w) {
            float ca = wa[i], cb = wb[i];
            pb = fmaf(ca, pb, cb);
            pa *= ca;
        }
    }
    eb = fmaf(xa, pb, xb);                    // combine(wavePrefix, laneExclusive)
    ea = pa * xa;
}

// Pass 1: per-block affine aggregate. Early-exits when the windowed-carry
// fast path applies (aggregates would never be read).
__global__ __launch_bounds__(BLOCK) void k_block_agg(
    const float* __restrict__ y, const float* __restrict__ alpha_p,
    float* __restrict__ aggA, float* __restrict__ aggB, long n)
{
    const float alpha = alpha_p[0];
    const float oma = 1.0f - alpha;
    if (pow2k(oma, 12) < DECAY_THR) return;   // fast path: skip pass 1 entirely

    const int t = threadIdx.x;
    const long base = (long)blockIdx.x * CHUNK + (long)t * SEG;

    float a = 1.0f, s = 0.0f;
    if (base + SEG <= n) {
        const float4* p = (const float4*)(y + base);
#pragma unroll
        for (int v = 0; v < VPT; ++v) {
            float4 q = p[v];
            s = fmaf(oma, s, alpha * q.x);
            s = fmaf(oma, s, alpha * q.y);
            s = fmaf(oma, s, alpha * q.z);
            s = fmaf(oma, s, alpha * q.w);
        }
        a = pow2k(oma, 5);                    // oma^SEG
    } else {
        for (int k = 0; k < SEG; ++k) {
            long idx = base + k;
            if (idx < n) { s = fmaf(oma, s, alpha * y[idx]); a *= oma; }
        }
    }

    __shared__ float wa[4], wb[4];
    wave_scan_affine(a, s);
    if ((t & 63) == 63) { wa[t >> 6] = a; wb[t >> 6] = s; }
    __syncthreads();
    if (t == 0) {
        float ta = 1.0f, tb = 0.0f;
#pragma unroll
        for (int i = 0; i < 4; ++i) {
            float ca = wa[i], cb = wb[i];
            tb = fmaf(ca, tb, cb);
            ta *= ca;
        }
        aggA[blockIdx.x] = ta;
        aggB[blockIdx.x] = tb;
    }
}

// Pass 2: carry from halo window (fast) or redundant aggregate scan (slow),
// then streaming replay with direct (L2-combined) float4 stores.
__global__ __launch_bounds__(BLOCK, 8) void k_emit(
    const float* __restrict__ y, const float* __restrict__ alpha_p,
    const float* __restrict__ aggA, const float* __restrict__ aggB,
    float* __restrict__ out, long n, int G)
{
    __shared__ float wa[4], wb[4];
    __shared__ float s_carry;

    const int t = threadIdx.x;
    // XCD-aware swizzle: consecutive tiles on one XCD. Bijective iff G%8==0.
    int tile = blockIdx.x;
    if ((G & 7) == 0) tile = (tile & 7) * (G >> 3) + (tile >> 3);

    const float alpha = alpha_p[0];
    const float oma   = 1.0f - alpha;
    const bool  fast  = (pow2k(oma, 12) < DECAY_THR);
    const long tbase = (long)tile * CHUNK;
    const long base  = tbase + (long)t * SEG;
    const bool fullTile = (tbase + CHUNK <= n);
    const float y0 = y[0];

    // ---- phase A: stream own segment -> per-thread affine (a_seg, b_seg) ----
    float a_seg, b_seg;
    if (fullTile) {
        const float4* p = (const float4*)(y + base);
        float s = 0.0f;
#pragma unroll
        for (int v = 0; v < VPT; ++v) {
            float4 q = p[v];
            s = fmaf(oma, s, alpha * q.x);
            s = fmaf(oma, s, alpha * q.y);
            s = fmaf(oma, s, alpha * q.z);
            s = fmaf(oma, s, alpha * q.w);
        }
        b_seg = s;
        a_seg = pow2k(oma, 5);                // oma^SEG
    } else {
        float a = 1.0f, s = 0.0f;
        for (int k = 0; k < SEG; ++k) {
            long idx = base + k;
            if (idx < n) { s = fmaf(oma, s, alpha * y[idx]); a *= oma; }
        }
        a_seg = a; b_seg = s;
    }

    // ---- fast-path carry: stream 4096-elem halo, wave scan + wave-total fold ----
    float carry = y0;                          // exact for tile 0
    if (fast) {
        if (tile > 0) {
            const float4* hp = (const float4*)(y + (tbase - HALO)) + t * HVPT;
            float hs = 0.0f;
#pragma unroll
            for (int v = 0; v < HVPT; ++v) {
                float4 q = hp[v];
                hs = fmaf(oma, hs, alpha * q.x);
                hs = fmaf(oma, hs, alpha * q.y);
                hs = fmaf(oma, hs, alpha * q.z);
                hs = fmaf(oma, hs, alpha * q.w);
            }
            float ha = pow2k(oma, 4);          // oma^HSEG
            wave_scan_affine(ha, hs);
            if ((t & 63) == 63) { wa[t >> 6] = ha; wb[t >> 6] = hs; }
            __syncthreads();
            float cb_ = 0.0f;                  // fold 4 wave totals; a-part ~0 dropped
#pragma unroll
            for (int i = 0; i < 4; ++i) {
                cb_ = fmaf(wa[i], cb_, wb[i]);
            }
            carry = cb_;                       // dropped term <= 1e-8 * |level|
            __syncthreads();                   // wa/wb reads done before reuse
        }
    }

    // ---- tile scan: per-thread exclusive prefix (uses wa/wb) ----
    float ea_th, eb_th;
    block_exscan_affine(a_seg, b_seg, wa, wb, t, ea_th, eb_th);

    if (!fast) {
        // ---- slow path: redundant scan of G aggregates -> this tile's carry ----
        const int items = (G + BLOCK - 1) / BLOCK;       // 8 for G=2048
        float ta = 1.0f, tb = 0.0f;
        for (int j = 0; j < items; ++j) {
            int g = t * items + j;
            if (g < G) {
                float ca = aggA[g], cb = aggB[g];
                tb = fmaf(ca, tb, cb);
                ta *= ca;
            }
        }
        __syncthreads();                       // wa/wb reads (tile scan) done
        float pa, pb;
        block_exscan_affine(ta, tb, wa, wb, t, pa, pb);
        const int q = tile / items;            // owning thread for this tile's prefix
        if (t == q) {
            float ea = pa, eb = pb;            // aggregates [0, q*items)
            const int r = tile - q * items;    // remaining [q*items, tile)
            for (int j = 0; j < r; ++j) {
                int g = q * items + j;
                float ca = aggA[g], cb = aggB[g];
                eb = fmaf(ca, eb, cb);
                ea *= ca;
            }
            s_carry = fmaf(ea, y0, eb);        // level just before this tile
        }
        __syncthreads();
        carry = s_carry;
    }

    float lvl = fmaf(ea_th, carry, eb_th);     // level just before this segment

    // ---- phase C: re-read own segment (L2/L3-hot), replay, direct stores ----
    if (fullTile) {
        const float4* p = (const float4*)(y + base);
        const bool guard = (base + SEG > n - 1);   // only threads touching index n-1
#pragma unroll
        for (int v = 0; v < VPT; ++v) {
            float4 q = p[v], r;
            lvl = fmaf(oma, lvl, alpha * q.x); r.x = lvl;
            lvl = fmaf(oma, lvl, alpha * q.y); r.y = lvl;
            lvl = fmaf(oma, lvl, alpha * q.z); r.z = lvl;
            lvl = fmaf(oma, lvl, alpha * q.w); r.w = lvl;
            const long gi = base + 4 * (long)v;
            if (!guard) {
                *(float4*)(out + gi) = r;          // non-NT: L2 combines same-line
            } else {
                if (gi + 4 <= n - 1) {
                    *(float4*)(out + gi) = r;
                } else {
                    if (gi + 0 < n - 1) out[gi + 0] = r.x;
                    if (gi + 1 < n - 1) out[gi + 1] = r.y;
                    if (gi + 2 < n - 1) out[gi + 2] = r.z;
                    if (gi + 3 < n - 1) out[gi + 3] = r.w;
                }
            }
        }
    } else {
        for (int k = 0; k < SEG; ++k) {
            long idx = base + k;
            if (idx < n) {
                lvl = fmaf(oma, lvl, alpha * y[idx]);
                if (idx < n - 1) out[idx] = lvl;
            }
        }
    }
}

extern "C" void kernel_launch(void* const* d_in, const int* in_sizes, int n_in,
                              void* d_out, int out_size, void* d_ws, size_t ws_size,
                              hipStream_t stream) {
    const float* y     = (const float*)d_in[0];
    const float* alpha = (const float*)d_in[1];
    float* out = (float*)d_out;
    const long n = (long)in_sizes[0];
    const int  G = (int)((n + CHUNK - 1) / CHUNK);   // 2048 for n = 2^24

    float* aggA = (float*)d_ws;        // G floats (written only on slow path)
    float* aggB = aggA + G;            // G floats

    k_block_agg<<<G, BLOCK, 0, stream>>>(y, alpha, aggA, aggB, n);
    k_emit<<<G, BLOCK, 0, stream>>>(y, alpha, aggA, aggB, out, n, G);
}

// Round 3
// 113.740 us; speedup vs baseline: 1.7557x; 1.7557x over previous
//
#include <hip/hip_runtime.h>
#include <stdint.h>

// Simple exponential smoothing: level_t = (1-a)*level_{t-1} + a*y_t,
// level_0 = y_0 pinned via global initial carry s_{-1} = y_0.
// out[t] = level_t for t in [0, n-2].
//
// R11: windowed-carry + LDS-EVERYTHING marshalling.
//   Ledger (fills ~85us fixed): R8 kernels 41.5us (agg 11 + emit 30),
//   R9 57us (spill: 64-float reg cache -> scratch, WRITE 105MB),
//   R10 118us (direct scattered stores -> L2 RMW, FETCH 256MB WRITE 137MB;
//   phase-C re-read missed L2: 8MB/XCD working set > 4MB).
//   R11 design: tile staged in LDS ONCE (32KB). Cooperative lane-contiguous
//   global loads -> LDS (XOR-swizzled float4 index j^((j>>3)&7): both
//   lane-contiguous and thread-segment access modes hit every bank group
//   uniformly -> conflict-free b128, no padding). Per-thread segment reduce
//   and replay read/write LDS in place; final cooperative lane-contiguous
//   NT store emits full 64B lines (R8's proven store path: no RMW, no cache
//   pollution). No bulk register state -> no spill.
//   Fast path iff (1-a)^4096 < 1e-8 (alpha > ~4.5e-3): per-block carry from
//   a 4096-elem halo (16MB total, same-XCD swizzle -> mostly L2-hit);
//   truncation <= 1e-8*|level|. Exact 2-pass aggregate path kept for tiny
//   alpha (k_block_agg early-exits on fast path).
// Bans (measured): in-kernel grid sync (R2 ~80us, R7 ~125us — cross-XCD
// coherence), coop launch (R4: graph-capture reject), per-thread direct
// float4 stores of contiguous segments (R10: L2 RMW inflation).
//
// Affine pairs (a,b): s_out = a*s_in + b.
// combine(earlier=(a1,b1), later=(a2,b2)) = (a1*a2, a2*b1 + b2).

#define BLOCK 256
#define SEG   32                  // elements per thread
#define VPT   (SEG / 4)           // 8 float4 per thread
#define CHUNK (BLOCK * SEG)       // 8192 elements per block
#define NF4   (CHUNK / 4)        // 2048 float4 slots in LDS
#define HALO  4096                // windowed-carry history length
#define HSEG  (HALO / BLOCK)      // 16 halo elements per thread
#define HVPT  (HSEG / 4)          // 4 float4 per thread for halo
#define DECAY_THR 1e-8f           // fast path iff (1-a)^HALO < this

typedef float f32x4 __attribute__((ext_vector_type(4)));

__device__ __forceinline__ void nt_store4(float* p, float x, float y, float z, float w) {
    f32x4 v = {x, y, z, w};
    __builtin_nontemporal_store(v, (f32x4*)p);
}

// Bank swizzle on float4 index (involution): spreads both access modes
// (lane-contiguous j=t+256k and thread-segment j=t*8+v) uniformly over the
// 8 bank groups (group = pj%8).
__device__ __forceinline__ int sw(int j) { return j ^ ((j >> 3) & 7); }

// x^(2^k) via repeated squaring
__device__ __forceinline__ float pow2k(float x, int k) {
    float p = x;
#pragma unroll
    for (int i = 0; i < k; ++i) p *= p;
    return p;
}

// Inclusive affine scan across the 64 lanes of a wave (shuffle-based).
__device__ __forceinline__ void wave_scan_affine(float& a, float& b) {
    const int lane = threadIdx.x & 63;
#pragma unroll
    for (int off = 1; off < 64; off <<= 1) {
        float pa = __shfl_up(a, off);
        float pb = __shfl_up(b, off);
        if (lane >= off) {
            b = fmaf(a, pb, b);   // later.a * earlier.b + later.b
            a = pa * a;
        }
    }
}

// Block-wide EXCLUSIVE affine scan (identity for t=0). wa/wb: 4-float LDS
// scratch; caller barriers before reuse. Internal barrier between write/read.
__device__ __forceinline__ void block_exscan_affine(
    float a, float b, float* wa, float* wb, int t, float& ea, float& eb)
{
    float ia = a, ib = b;
    wave_scan_affine(ia, ib);                 // inclusive within wave
    const int w = t >> 6, lane = t & 63;
    if (lane == 63) { wa[w] = ia; wb[w] = ib; }
    float xa = __shfl_up(ia, 1);
    float xb = __shfl_up(ib, 1);
    if (lane == 0) { xa = 1.0f; xb = 0.0f; }
    __syncthreads();
    float pa = 1.0f, pb = 0.0f;               // compose waves 0..w-1 in order
#pragma unroll
    for (int i = 0; i < 3; ++i) {
        if (i < w) {
            float ca = wa[i], cb = wb[i];
            pb = fmaf(ca, pb, cb);
            pa *= ca;
        }
    }
    eb = fmaf(xa, pb, xb);                    // combine(wavePrefix, laneExclusive)
    ea = pa * xa;
}

// Pass 1: per-block affine aggregate. Early-exits when the windowed-carry
// fast path applies (aggregates would never be read).
__global__ __launch_bounds__(BLOCK) void k_block_agg(
    const float* __restrict__ y, const float* __restrict__ alpha_p,
    float* __restrict__ aggA, float* __restrict__ aggB, long n)
{
    const float alpha = alpha_p[0];
    const float oma = 1.0f - alpha;
    if (pow2k(oma, 12) < DECAY_THR) return;   // fast path: skip pass 1 entirely

    const int t = threadIdx.x;
    const long base = (long)blockIdx.x * CHUNK + (long)t * SEG;

    float a = 1.0f, s = 0.0f;
    if (base + SEG <= n) {
        const float4* p = (const float4*)(y + base);
#pragma unroll
        for (int v = 0; v < VPT; ++v) {
            float4 q = p[v];
            s = fmaf(oma, s, alpha * q.x);
            s = fmaf(oma, s, alpha * q.y);
            s = fmaf(oma, s, alpha * q.z);
            s = fmaf(oma, s, alpha * q.w);
        }
        a = pow2k(oma, 5);                    // oma^SEG
    } else {
        for (int k = 0; k < SEG; ++k) {
            long idx = base + k;
            if (idx < n) { s = fmaf(oma, s, alpha * y[idx]); a *= oma; }
        }
    }

    __shared__ float wa[4], wb[4];
    wave_scan_affine(a, s);
    if ((t & 63) == 63) { wa[t >> 6] = a; wb[t >> 6] = s; }
    __syncthreads();
    if (t == 0) {
        float ta = 1.0f, tb = 0.0f;
#pragma unroll
        for (int i = 0; i < 4; ++i) {
            float ca = wa[i], cb = wb[i];
            tb = fmaf(ca, tb, cb);
            ta *= ca;
        }
        aggA[blockIdx.x] = ta;
        aggB[blockIdx.x] = tb;
    }
}

// Pass 2: carry from halo (fast) or aggregate scan (slow); tile marshalled
// through swizzled LDS; cooperative NT stores.
__global__ __launch_bounds__(BLOCK, 4) void k_emit(
    const float* __restrict__ y, const float* __restrict__ alpha_p,
    const float* __restrict__ aggA, const float* __restrict__ aggB,
    float* __restrict__ out, long n, int G)
{
    __shared__ float4 buf[NF4];          // 32 KB tile stage (in, then out)
    __shared__ float wa[4], wb[4];
    __shared__ float s_carry;

    const int t = threadIdx.x;
    // XCD-aware swizzle: consecutive tiles on one XCD. Bijective iff G%8==0.
    int tile = blockIdx.x;
    if ((G & 7) == 0) tile = (tile & 7) * (G >> 3) + (tile >> 3);

    const float alpha = alpha_p[0];
    const float oma   = 1.0f - alpha;
    const bool  fast  = (pow2k(oma, 12) < DECAY_THR);
    const long tbase = (long)tile * CHUNK;
    const long base  = tbase + (long)t * SEG;
    const bool fullTile = (tbase + CHUNK <= n);
    const float y0 = y[0];

    // ---- issue halo loads first (independent, long-latency) ----
    const bool do_halo = fast && (tile > 0);  // tile>0 => tbase >= CHUNK >= HALO
    float4 hq[HVPT];
    if (do_halo) {
        const float4* hp = (const float4*)(y + (tbase - HALO)) + t * HVPT;
#pragma unroll
        for (int v = 0; v < HVPT; ++v) hq[v] = hp[v];
    }

    // ---- cooperative tile load -> swizzled LDS (lane-contiguous global) ----
    if (fullTile) {
        const float4* p4 = (const float4*)(y + tbase);
        float4 tmp[8];
#pragma unroll
        for (int k = 0; k < 8; ++k) tmp[k] = p4[t + (k << 8)];
#pragma unroll
        for (int k = 0; k < 8; ++k) buf[sw(t + (k << 8))] = tmp[k];
    }

    // ---- fast-path carry: halo reduce + wave scan + wave-total fold ----
    float carry = y0;                          // exact for tile 0
    if (do_halo) {
        float hs = 0.0f;
#pragma unroll
        for (int v = 0; v < HVPT; ++v) {
            float4 q = hq[v];
            hs = fmaf(oma, hs, alpha * q.x);
            hs = fmaf(oma, hs, alpha * q.y);
            hs = fmaf(oma, hs, alpha * q.z);
            hs = fmaf(oma, hs, alpha * q.w);
        }
        float ha = pow2k(oma, 4);              // oma^HSEG
        wave_scan_affine(ha, hs);
        if ((t & 63) == 63) { wa[t >> 6] = ha; wb[t >> 6] = hs; }
        __syncthreads();
        float cb_ = 0.0f;                      // fold 4 wave totals; a-term ~0 dropped
#pragma unroll
        for (int i = 0; i < 4; ++i) cb_ = fmaf(wa[i], cb_, wb[i]);
        carry = cb_;                           // dropped term <= 1e-8 * |level|
    }

    __syncthreads();   // buf (tile) visible to all; wa/wb free for exscan

    // ---- per-thread segment reduce from LDS ----
    float a_seg, b_seg;
    if (fullTile) {
        float s = 0.0f;
#pragma unroll
        for (int v = 0; v < VPT; ++v) {
            float4 q = buf[sw(t * VPT + v)];
            s = fmaf(oma, s, alpha * q.x);
            s = fmaf(oma, s, alpha * q.y);
            s = fmaf(oma, s, alpha * q.z);
            s = fmaf(oma, s, alpha * q.w);
        }
        b_seg = s;
        a_seg = pow2k(oma, 5);                 // oma^SEG
    } else {
        float a = 1.0f, s = 0.0f;
        for (int k = 0; k < SEG; ++k) {
            long idx = base + k;
            if (idx < n) { s = fmaf(oma, s, alpha * y[idx]); a *= oma; }
        }
        a_seg = a; b_seg = s;
    }

    // ---- tile exclusive scan ----
    float ea_th, eb_th;
    block_exscan_affine(a_seg, b_seg, wa, wb, t, ea_th, eb_th);

    if (!fast) {
        // ---- slow path: redundant scan of G aggregates -> this tile's carry ----
        const int items = (G + BLOCK - 1) / BLOCK;
        float ta = 1.0f, tb = 0.0f;
        for (int j = 0; j < items; ++j) {
            int g = t * items + j;
            if (g < G) {
                float ca = aggA[g], cb = aggB[g];
                tb = fmaf(ca, tb, cb);
                ta *= ca;
            }
        }
        __syncthreads();                       // wa/wb reads (tile scan) done
        float pa, pb;
        block_exscan_affine(ta, tb, wa, wb, t, pa, pb);
        const int q = tile / items;            // owning thread for this tile's prefix
        if (t == q) {
            float ea = pa, eb = pb;            // aggregates [0, q*items)
            const int r = tile - q * items;    // remaining [q*items, tile)
            for (int j = 0; j < r; ++j) {
                int g = q * items + j;
                float ca = aggA[g], cb = aggB[g];
                eb = fmaf(ca, eb, cb);
                ea *= ca;
            }
            s_carry = fmaf(ea, y0, eb);        // level just before this tile
        }
        __syncthreads();
        carry = s_carry;
    }

    float lvl = fmaf(ea_th, carry, eb_th);     // level just before this segment

    // ---- replay from LDS, write results back in place (own slots only) ----
    if (fullTile) {
#pragma unroll
        for (int v = 0; v < VPT; ++v) {
            const int pj = sw(t * VPT + v);
            float4 q = buf[pj], r;
            lvl = fmaf(oma, lvl, alpha * q.x); r.x = lvl;
            lvl = fmaf(oma, lvl, alpha * q.y); r.y = lvl;
            lvl = fmaf(oma, lvl, alpha * q.z); r.z = lvl;
            lvl = fmaf(oma, lvl, alpha * q.w); r.w = lvl;
            buf[pj] = r;
        }
        __syncthreads();   // all replay writes visible
        // ---- cooperative lane-contiguous NT store (full 64B lines) ----
        const bool lastGuard = (tbase + CHUNK > n - 1);
#pragma unroll
        for (int k = 0; k < 8; ++k) {
            const int j = t + (k << 8);
            float4 r = buf[sw(j)];
            const long gi = tbase + 4L * j;
            if (!lastGuard) {
                nt_store4(out + gi, r.x, r.y, r.z, r.w);
            } else {
                if (gi + 4 <= n - 1) {
                    nt_store4(out + gi, r.x, r.y, r.z, r.w);
                } else {
                    if (gi + 0 < n - 1) out[gi + 0] = r.x;
                    if (gi + 1 < n - 1) out[gi + 1] = r.y;
                    if (gi + 2 < n - 1) out[gi + 2] = r.z;
                    if (gi + 3 < n - 1) out[gi + 3] = r.w;
                }
            }
        }
    } else {
        for (int k = 0; k < SEG; ++k) {
            long idx = base + k;
            if (idx < n) {
                lvl = fmaf(oma, lvl, alpha * y[idx]);
                if (idx < n - 1) out[idx] = lvl;
            }
        }
    }
}

extern "C" void kernel_launch(void* const* d_in, const int* in_sizes, int n_in,
                              void* d_out, int out_size, void* d_ws, size_t ws_size,
                              hipStream_t stream) {
    const float* y     = (const float*)d_in[0];
    const float* alpha = (const float*)d_in[1];
    float* out = (float*)d_out;
    const long n = (long)in_sizes[0];
    const int  G = (int)((n + CHUNK - 1) / CHUNK);   // 2048 for n = 2^24

    float* aggA = (float*)d_ws;        // G floats (written only on slow path)
    float* aggB = aggA + G;            // G floats

    k_block_agg<<<G, BLOCK, 0, stream>>>(y, alpha, aggA, aggB, n);
    k_emit<<<G, BLOCK, 0, stream>>>(y, alpha, aggA, aggB, out, n, G);
}